// Round 1
// 127.699 us; speedup vs baseline: 1.0160x; 1.0160x over previous
//
#include <hip/hip_runtime.h>
#include <hip/hip_bf16.h>

typedef unsigned int u32;
typedef unsigned short u16;

#define TOKENS 512
#define OUT_F  8192
#define IN_F   4096
#define KPACK  (IN_F / 4)
#define TMB 128              // block m-tile
#define TNB 128              // block n-tile
#define BKW 128              // k per window
#define NWIN (IN_F / BKW)    // 32
#define NPAIR (NWIN / 2)     // 16

typedef __attribute__((ext_vector_type(8))) short bf16x8;
typedef __attribute__((ext_vector_type(4))) float f32x4;
typedef __attribute__((ext_vector_type(16))) float f32x16;

__device__ __forceinline__ u32 pack_bf16x2(float a, float b) {
    __hip_bfloat162 h = __float22bfloat162_rn(make_float2(a, b));
    union { __hip_bfloat162 h2; u32 u; } cvt;
    cvt.h2 = h;
    return cvt.u;
}

// 2 codes (4 bits) -> 2 packed bf16 via byte-table v_perm.
// code 0 -> 0xBF80 (-1), 2 -> 0x3F80 (+1), 1/3 -> 0x0000.
__device__ __forceinline__ u32 decode_pair(u32 d) {
    u32 s = (__umul24(d, 0x808202u) & 0x06060606u) + 0x01000100u;
    return __builtin_amdgcn_perm(0x00003F80u, 0x0000BF80u, s);
}
// 16 bits (8 consecutive-k codes) at bit offset sh of w -> B fragment.
__device__ __forceinline__ bf16x8 decode_frag(u32 w, int sh) {
    union { bf16x8 v; u32 u[4]; } c;
    c.u[0] = decode_pair((w >> (sh + 0)) & 0xFu);
    c.u[1] = decode_pair((w >> (sh + 4)) & 0xFu);
    c.u[2] = decode_pair((w >> (sh + 8)) & 0xFu);
    c.u[3] = decode_pair((w >> (sh + 12)) & 0xFu);
    return c.v;
}

__device__ __forceinline__ void async_ld16(const void* g, void* l) {
    __builtin_amdgcn_global_load_lds(
        (const __attribute__((address_space(1))) u32*)g,
        (__attribute__((address_space(3))) u32*)l, 16, 0, 0);
}

// ---- pre-pass 1: X fp32 -> bf16 (row-major) ----
__global__ __launch_bounds__(256) void convert_x(const float* __restrict__ X,
                                                 u16* __restrict__ Xb) {
    int i = (blockIdx.x * 256 + threadIdx.x) * 8;
    float4 a = *(const float4*)(X + i);
    float4 b = *(const float4*)(X + i + 4);
    uint4 q;
    q.x = pack_bf16x2(a.x, a.y);
    q.y = pack_bf16x2(a.z, a.w);
    q.z = pack_bf16x2(b.x, b.y);
    q.w = pack_bf16x2(b.z, b.w);
    *(uint4*)(Xb + i) = q;
}

// ---- pre-pass 2: repack W2 -> dense 2-bit fragment-major, window-PAIRED (W8) ----
// W8 uint4 idx = ((((ngrp*2+nh)*4 + kq)*16 + p)*64 + lane, pair p = windows 2p, 2p+1
//  .xy = uint2 for window 2p   (x: col c0 = ngrp*128+nh*64+(lane&31), y: col c0+32)
//  .zw = uint2 for window 2p+1
//  Each u16 of a uint2 half: 8 codes, k = w*128 + kq*32 + ksub*16 + (lane>>5)*8 .. +7
__global__ __launch_bounds__(256) void repack_w8(const u32* __restrict__ W2,
                                                 uint4* __restrict__ W8) {
    __shared__ u32 dense[128 * 32];    // 16 KB; dense[col*32 + (j ^ (col&31))]
    const int ngrp = blockIdx.x;       // 64 col-groups of 128
    const int kc   = blockIdx.y;       // 8 k-chunks of 512 codes (4 windows = 2 pairs)
    const int t = threadIdx.x;
#pragma unroll
    for (int i = 0; i < 16; ++i) {     // phase 1: coalesced uint4 reads
        int id = t + 256 * i;
        int col = id >> 5, jq = id & 31;
        uint4 wv = *(const uint4*)(W2 + (size_t)(ngrp * 128 + col) * KPACK + kc * 128 + jq * 4);
        dense[col * 32 + (jq ^ (col & 31))] =
            (wv.x & 0xFFu) | ((wv.y & 0xFFu) << 8) | ((wv.z & 0xFFu) << 16) | ((wv.w & 0xFFu) << 24);
    }
    __syncthreads();
    const u16* sp = (const u16*)dense;
#pragma unroll
    for (int p = 0; p < 4; ++p) {      // phase 2: coalesced uint4 writes
        int e = t + 256 * p;           // 0..1023 uint4 outputs
        int lane = e & 63;
        int kq = (e >> 6) & 3;
        int wp2 = (e >> 8) & 1;        // which window-pair within this kc
        int nh = (e >> 9) & 1;
        int h = lane >> 5;
        int c0 = nh * 64 + (lane & 31), c1 = c0 + 32;
        u32 ov[4];
#pragma unroll
        for (int ws = 0; ws < 2; ++ws) {
            int wloc = wp2 * 2 + ws;
            int j0 = wloc * 8 + kq * 2;
            u32 x0 = sp[((c0 * 32 + (j0 ^ (c0 & 31))) << 1) | h];
            u32 x1 = sp[((c0 * 32 + ((j0 + 1) ^ (c0 & 31))) << 1) | h];
            u32 y0 = sp[((c1 * 32 + (j0 ^ (c1 & 31))) << 1) | h];
            u32 y1 = sp[((c1 * 32 + ((j0 + 1) ^ (c1 & 31))) << 1) | h];
            ov[ws * 2 + 0] = x0 | (x1 << 16);
            ov[ws * 2 + 1] = y0 | (y1 << 16);
        }
        uint4 q = make_uint4(ov[0], ov[1], ov[2], ov[3]);
        int pr = kc * 2 + wp2;         // global pair index 0..15
        W8[((((size_t)(ngrp * 2 + nh) * 4 + kq) * 16) + pr) * 64 + lane] = q;
    }
}

// ---- main GEMM: 128x128 block, 512 thr, 8 waves = 4 kq x 2 nh, mt=4,
//      BK=128 windows, 1 block/CU.
//      T3/T4 pipeline: 4 A window-buffers + 2 B pair-buffers, ALL global traffic
//      via global_load_lds, one raw s_barrier per window, counted vmcnt (never 0
//      in steady state), setprio around MFMA clusters. ----
__global__ __launch_bounds__(512, 2) void ternary_gemm9(
    const u16* __restrict__ Xb,
    const uint4* __restrict__ W8,
    const float* __restrict__ alpha,
    const float* __restrict__ bias,
    float* __restrict__ Out)
{
    __shared__ u16 As[4 * TMB * BKW];  // 4 x 32 KB window buffers; epilogue reuses as scratch
    __shared__ uint4 Bs[2 * 512];      // 2 x 8 KB pair buffers (per wave: 64 lanes x 16 B)

    const int tid  = threadIdx.x;
    const int lane = tid & 63;
    const int wave = tid >> 6;
    const int kq = wave & 3;           // k-quarter (32 of each 128-k window)
    const int nh = wave >> 2;          // n-half (64 cols)

    const int m0 = blockIdx.x * TMB;   // 4 m-tiles; XCD-local via round-robin dispatch
    const int ngrp = blockIdx.y;
    const int n0 = ngrp * TNB;

    f32x16 acc[4][2];
#pragma unroll
    for (int mt = 0; mt < 4; ++mt)
#pragma unroll
        for (int nt = 0; nt < 2; ++nt)
#pragma unroll
            for (int i = 0; i < 16; ++i)
                acc[mt][nt][i] = 0.f;

    // A staging: wave stages rows [wave*16, wave*16+16), 4 insts x 4 rows.
    // Row = 128 k = 16 chunks of 16 B; chunk c stored at slot c ^ (row&15).
    const u16* ga[4];
    u32 lbase[4];
#pragma unroll
    for (int i = 0; i < 4; ++i) {
        int rbase = wave * 16 + i * 4;
        int row = rbase + (lane >> 4);
        int cd = (lane & 15) ^ (row & 15);
        ga[i] = Xb + (size_t)(m0 + row) * IN_F + cd * 8;
        lbase[i] = rbase * BKW;
    }

    // A-fragment LDS offsets (u16 units); row&15 == lane&15 since mt*32 ≡ 0 mod 16
    int ofsA[4][2];
#pragma unroll
    for (int mt = 0; mt < 4; ++mt)
#pragma unroll
        for (int ks = 0; ks < 2; ++ks) {
            int row = mt * 32 + (lane & 31);
            int chunk = kq * 4 + ks * 2 + (lane >> 5);
            ofsA[mt][ks] = row * BKW + ((chunk ^ (row & 15))) * 8;
        }

    // B source: per-lane uint4 (one window-pair); per-wave LDS slot base.
    const uint4* w8p = W8 + ((((size_t)(ngrp * 2 + nh) * 4 + kq) * 16) * 64) + lane;
    uint4* const bsb = Bs + wave * 64;

    auto issueA = [&](int w) {
        u16* dst = As + (size_t)((w & 3) * (TMB * BKW));
        const int koff = w * BKW;
#pragma unroll
        for (int i = 0; i < 4; ++i)
            async_ld16(ga[i] + koff, dst + lbase[i]);
    };
    auto issueB = [&](int p) {
        async_ld16(w8p + (size_t)p * 64, bsb + (p & 1) * 512);
    };

    auto window_compute = [&](int wmod4, u32 wx, u32 wy) {
        const u16* ab = As + (size_t)wmod4 * (TMB * BKW);
#pragma unroll
        for (int ks = 0; ks < 2; ++ks) {
            bf16x8 a0 = *(const bf16x8*)(ab + ofsA[0][ks]);
            bf16x8 a1 = *(const bf16x8*)(ab + ofsA[1][ks]);
            bf16x8 a2 = *(const bf16x8*)(ab + ofsA[2][ks]);
            bf16x8 a3 = *(const bf16x8*)(ab + ofsA[3][ks]);
            bf16x8 b0 = decode_frag(wx, ks * 16);
            bf16x8 b1 = decode_frag(wy, ks * 16);
            __builtin_amdgcn_s_setprio(1);
            acc[0][0] = __builtin_amdgcn_mfma_f32_32x32x16_bf16(a0, b0, acc[0][0], 0, 0, 0);
            acc[1][0] = __builtin_amdgcn_mfma_f32_32x32x16_bf16(a1, b0, acc[1][0], 0, 0, 0);
            acc[2][0] = __builtin_amdgcn_mfma_f32_32x32x16_bf16(a2, b0, acc[2][0], 0, 0, 0);
            acc[3][0] = __builtin_amdgcn_mfma_f32_32x32x16_bf16(a3, b0, acc[3][0], 0, 0, 0);
            acc[0][1] = __builtin_amdgcn_mfma_f32_32x32x16_bf16(a0, b1, acc[0][1], 0, 0, 0);
            acc[1][1] = __builtin_amdgcn_mfma_f32_32x32x16_bf16(a1, b1, acc[1][1], 0, 0, 0);
            acc[2][1] = __builtin_amdgcn_mfma_f32_32x32x16_bf16(a2, b1, acc[2][1], 0, 0, 0);
            acc[3][1] = __builtin_amdgcn_mfma_f32_32x32x16_bf16(a3, b1, acc[3][1], 0, 0, 0);
            __builtin_amdgcn_s_setprio(0);
        }
    };

    // vmcnt-wait then barrier: each wave certifies its own DMAs done, barrier
    // certifies all waves. "memory" clobber pins DMA issues above / LDS reads
    // below; sched_barrier pins the machine scheduler.
#define WAIT_BARRIER(N) do {                                         \
        asm volatile("s_waitcnt vmcnt(" #N ")" ::: "memory");        \
        __builtin_amdgcn_s_barrier();                                \
        __builtin_amdgcn_sched_barrier(0);                           \
    } while (0)

    // Prologue issue order matters for FIFO vmcnt counting: A(0), B(0), A(1).
    issueA(0);
    issueB(0);
    issueA(1);

    uint4 bv;
    // Steady state per wave: in flight at the wait = A(w+1):4 + A(w+2):4 + B(p+1):1 = 9.
#pragma unroll 1
    for (int p = 0; p < NPAIR - 2; ++p) {   // pairs 0..13 = windows 0..27
        const int w = 2 * p;
        issueA(w + 2);
        issueB(p + 1);
        WAIT_BARRIER(9);
        bv = *(const uint4*)(Bs + (p & 1) * 512 + wave * 64 + lane);
        window_compute(w & 3, bv.x, bv.y);
        issueA(w + 3);
        WAIT_BARRIER(9);
        window_compute((w + 1) & 3, bv.z, bv.w);
    }
    // w=28 (pair 14)
    issueA(30);
    issueB(15);
    WAIT_BARRIER(9);
    bv = *(const uint4*)(Bs + 0 * 512 + wave * 64 + lane);
    window_compute(28 & 3, bv.x, bv.y);
    // w=29
    issueA(31);
    WAIT_BARRIER(9);
    window_compute(29 & 3, bv.z, bv.w);
    // w=30 (pair 15): drain through B(15); only A(31) may remain in flight
    WAIT_BARRIER(4);
    bv = *(const uint4*)(Bs + 1 * 512 + wave * 64 + lane);
    window_compute(30 & 3, bv.x, bv.y);
    // w=31: final drain
    WAIT_BARRIER(0);
    window_compute(31 & 3, bv.z, bv.w);
#undef WAIT_BARRIER

    // ---- 4-way kq reduction through LDS (3 staggered rounds, 64 KB scratch) ----
    // Scratch = As[0..64KB) = window buffers 0,1 (last read at windows 28/29,
    // certified done by the w=30/31 barriers; window 31 reads buffer 3 only).
    f32x4* red = (f32x4*)As;           // 4096 f32x4 = 64 KB
#pragma unroll 1
    for (int q = 1; q < 4; ++q) {
        if (kq == q) {
            f32x4* dst = red + nh * 2048 + lane;
#pragma unroll
            for (int mt = 0; mt < 4; ++mt)
#pragma unroll
                for (int nt = 0; nt < 2; ++nt)
#pragma unroll
                    for (int sub = 0; sub < 4; ++sub) {
                        f32x4 v = {acc[mt][nt][sub * 4 + 0], acc[mt][nt][sub * 4 + 1],
                                   acc[mt][nt][sub * 4 + 2], acc[mt][nt][sub * 4 + 3]};
                        dst[(mt * 8 + nt * 4 + sub) * 64] = v;
                    }
        }
        __syncthreads();
        if (kq == 0) {
            const f32x4* src = red + nh * 2048 + lane;
#pragma unroll
            for (int mt = 0; mt < 4; ++mt)
#pragma unroll
                for (int nt = 0; nt < 2; ++nt)
#pragma unroll
                    for (int sub = 0; sub < 4; ++sub) {
                        f32x4 v = src[(mt * 8 + nt * 4 + sub) * 64];
#pragma unroll
                        for (int i = 0; i < 4; ++i)
                            acc[mt][nt][sub * 4 + i] += v[i];
                    }
        }
        __syncthreads();
    }

    // ---- epilogue (kq==0 waves): alpha*acc + bias ----
    if (kq == 0) {
#pragma unroll
        for (int nt = 0; nt < 2; ++nt) {
            int ncol = n0 + nh * 64 + nt * 32 + (lane & 31);
            float av = alpha[ncol];
            float bv2 = bias[ncol];
#pragma unroll
            for (int mt = 0; mt < 4; ++mt) {
#pragma unroll
                for (int r = 0; r < 16; ++r) {
                    int row = m0 + mt * 32 + (r & 3) + 8 * (r >> 2) + 4 * (lane >> 5);
                    Out[(size_t)row * OUT_F + ncol] = acc[mt][nt][r] * av + bv2;
                }
            }
        }
    }
}

// ---- naive fallback (workspace too small; correctness only) ----
__global__ void ternary_naive(const float* __restrict__ X, const u32* __restrict__ W2,
                              const float* __restrict__ alpha, const float* __restrict__ bias,
                              float* __restrict__ Out) {
    int o  = blockIdx.x * 64 + (threadIdx.x & 63);
    int tk = blockIdx.y * 4 + (threadIdx.x >> 6);
    const float* x = X + (size_t)tk * IN_F;
    const u32* w = W2 + (size_t)o * KPACK;
    float s = 0.f;
    for (int d = 0; d < KPACK; ++d) {
        u32 b = w[d] & 0xFFu;
        const float* xp = x + d * 4;
#pragma unroll
        for (int j = 0; j < 4; ++j) {
            u32 c = (b >> (2 * j)) & 3u;
            float wv = (c == 2u) ? 1.f : ((c == 0u) ? -1.f : 0.f);
            s += xp[j] * wv;
        }
    }
    Out[(size_t)tk * OUT_F + o] = s * alpha[o] + bias[o];
}

extern "C" void kernel_launch(void* const* d_in, const int* in_sizes, int n_in,
                              void* d_out, int out_size, void* d_ws, size_t ws_size,
                              hipStream_t stream) {
    const float* x = (const float*)d_in[0];
    const u32* w2 = (const u32*)d_in[1];
    const float* alpha = (const float*)d_in[2];
    const float* bias  = (const float*)d_in[3];
    float* out = (float*)d_out;

    const size_t xb_bytes = (size_t)TOKENS * IN_F * sizeof(u16);   // 4 MB
    const size_t w8_bytes = (size_t)OUT_F * IN_F / 4;              // 8 MB

    if (ws_size >= xb_bytes + w8_bytes) {
        u16* xb = (u16*)d_ws;
        uint4* w8 = (uint4*)((char*)d_ws + xb_bytes);
        convert_x<<<(TOKENS * IN_F) / (256 * 8), 256, 0, stream>>>(x, xb);
        repack_w8<<<dim3(64, 8), 256, 0, stream>>>(w2, w8);
        ternary_gemm9<<<dim3(TOKENS / TMB, OUT_F / TNB), 512, 0, stream>>>(xb, w8, alpha, bias, out);
    } else {
        ternary_naive<<<dim3(OUT_F / 64, TOKENS / 4), 256, 0, stream>>>(x, w2, alpha, bias, out);
    }
}